// Round 2
// baseline (152.829 us; speedup 1.0000x reference)
//
#include <hip/hip_runtime.h>
#include <cmath>

// Masked decode-GEMV: y[n] = sum_z m_z * x_z * W_t[z,n],
// m_z = (|x_z| * ||W_t[z,:]|| >= thresh).
// Two-pass: (A) row-norm + mask -> xm[z] in d_ws, (B) masked GEMV skipping
// zeroed rows (second read mostly served by the 256 MB L3).

#define ZDIM 14336
#define NDIM 4096
#define NF4  (NDIM / 4)   // 1024 float4 per row

// ---------------- Kernel A: row norms + mask ----------------
// one block per row; 256 threads x 4 float4 = the whole 4096-float row.
// Pure streaming reduce: 14336 blocks -> 32 resident waves/CU, latency
// fully hidden by TLP; no post-barrier register reuse.
__global__ __launch_bounds__(256) void rownorm_mask(
    const float* __restrict__ x,
    const float* __restrict__ Wt,
    const float* __restrict__ thresh,
    float* __restrict__ xm) {
  const int t = threadIdx.x;
  const int z = blockIdx.x;
  const float4* __restrict__ row =
      reinterpret_cast<const float4*>(Wt) + (size_t)z * NF4;

  const float4 w0 = row[t];
  const float4 w1 = row[t + 256];
  const float4 w2 = row[t + 512];
  const float4 w3 = row[t + 768];

  float ss = 0.0f;
  ss += w0.x * w0.x + w0.y * w0.y + w0.z * w0.z + w0.w * w0.w;
  ss += w1.x * w1.x + w1.y * w1.y + w1.z * w1.z + w1.w * w1.w;
  ss += w2.x * w2.x + w2.y * w2.y + w2.z * w2.z + w2.w * w2.w;
  ss += w3.x * w3.x + w3.y * w3.y + w3.z * w3.z + w3.w * w3.w;

  // wave-64 reduce
  #pragma unroll
  for (int off = 32; off > 0; off >>= 1) ss += __shfl_down(ss, off, 64);

  __shared__ float red[4];
  if ((t & 63) == 0) red[t >> 6] = ss;
  __syncthreads();

  if (t == 0) {
    const float n2 = red[0] + red[1] + red[2] + red[3];
    const float xz = x[z];
    xm[z] = (fabsf(xz) * sqrtf(n2) >= thresh[0]) ? xz : 0.0f;
  }
}

// ---------------- Kernel B: masked GEMV ----------------
// grid (ZDIM/ROWS_B, 2): block owns 16 rows x 2048 columns.
// No barriers, no reduce; uniform skip of masked rows; register acc;
// one atomicAdd per output element per block at the end.
#define ROWS_B 16
#define CPB_F4 512   // float4 columns per block (= 2048 floats)

__global__ __launch_bounds__(256) void masked_gemv(
    const float* __restrict__ xm,
    const float* __restrict__ Wt,
    float* __restrict__ y) {
  const int t    = threadIdx.x;
  const int row0 = blockIdx.x * ROWS_B;
  const int cb   = blockIdx.y * CPB_F4;  // float4 column offset
  const float4* __restrict__ W4 = reinterpret_cast<const float4*>(Wt);

  // block-uniform masked-x values (L2-resident broadcast loads)
  float xv[ROWS_B];
  #pragma unroll
  for (int r = 0; r < ROWS_B; ++r) xv[r] = xm[row0 + r];

  float4 a0 = {0.f, 0.f, 0.f, 0.f};
  float4 a1 = {0.f, 0.f, 0.f, 0.f};

  #pragma unroll
  for (int r = 0; r < ROWS_B; ++r) {
    const float xz = xv[r];
    if (xz != 0.0f) {  // uniform branch: whole block skips masked rows
      const float4* __restrict__ rp =
          W4 + (size_t)(row0 + r) * NF4 + cb + t;
      const float4 w0 = rp[0];
      const float4 w1 = rp[256];
      a0.x = fmaf(xz, w0.x, a0.x);
      a0.y = fmaf(xz, w0.y, a0.y);
      a0.z = fmaf(xz, w0.z, a0.z);
      a0.w = fmaf(xz, w0.w, a0.w);
      a1.x = fmaf(xz, w1.x, a1.x);
      a1.y = fmaf(xz, w1.y, a1.y);
      a1.z = fmaf(xz, w1.z, a1.z);
      a1.w = fmaf(xz, w1.w, a1.w);
    }
  }

  const int c0 = (cb + t) * 4;
  const int c1 = (cb + t + 256) * 4;
  atomicAdd(&y[c0 + 0], a0.x);
  atomicAdd(&y[c0 + 1], a0.y);
  atomicAdd(&y[c0 + 2], a0.z);
  atomicAdd(&y[c0 + 3], a0.w);
  atomicAdd(&y[c1 + 0], a1.x);
  atomicAdd(&y[c1 + 1], a1.y);
  atomicAdd(&y[c1 + 2], a1.z);
  atomicAdd(&y[c1 + 3], a1.w);
}

extern "C" void kernel_launch(void* const* d_in, const int* in_sizes, int n_in,
                              void* d_out, int out_size, void* d_ws, size_t ws_size,
                              hipStream_t stream) {
  const float* x      = (const float*)d_in[0];  // [1,1,Z]
  const float* Wt     = (const float*)d_in[1];  // [Z,N]
  const float* thresh = (const float*)d_in[2];  // [1]
  float* y            = (float*)d_out;          // [1,1,N]
  float* xm           = (float*)d_ws;           // [Z] masked x (57 KB scratch)

  // harness does NOT re-zero d_out between timed replays
  hipMemsetAsync(y, 0, (size_t)out_size * sizeof(float), stream);

  rownorm_mask<<<ZDIM, 256, 0, stream>>>(x, Wt, thresh, xm);

  dim3 gridB(ZDIM / ROWS_B, NDIM / (CPB_F4 * 4));  // (896, 2)
  masked_gemv<<<gridB, 256, 0, stream>>>(xm, Wt, y);
}

// Round 3
// 70.534 us; speedup vs baseline: 2.1668x; 2.1668x over previous
//
#include <hip/hip_runtime.h>
#include <cmath>

// Masked decode-GEMV: y[n] = sum_z m_z * x_z * W_t[z,n],
// m_z = (|x_z| * ||W_t[z,:]||_2 >= thresh).
//
// Three deterministic passes, NO atomics (same-address atomicAdd contention
// on the 16 KB output was the suspected ~100us floor in rounds 1-2):
//   A: wave-per-row norms -> xm[z] = mask ? x[z] : 0        (reads W once)
//   B: masked GEMV -> per-zchunk partials in d_ws            (reads ~half of W, L3-hot)
//   C: reduce partials -> y                                  (3.7 MB, L2)

#define ZDIM 14336
#define NDIM 4096
#define NF4  (NDIM / 4)       // 1024 float4 per row

// ---------------- Kernel A: row norms + mask (wave per row) ----------------
// 4 waves/block, one row per wave, no barriers. Lane l reads row[l + 64k],
// k=0..15 (fully coalesced 1KB/instr), shfl-butterfly reduce, lane0 writes.
__global__ __launch_bounds__(256) void rownorm_mask(
    const float* __restrict__ x,
    const float* __restrict__ Wt,
    const float* __restrict__ thresh,
    float* __restrict__ xm) {
  const int lane = threadIdx.x & 63;
  const int z    = blockIdx.x * 4 + (threadIdx.x >> 6);
  const float4* __restrict__ row =
      reinterpret_cast<const float4*>(Wt) + (size_t)z * NF4 + lane;

  float ss = 0.0f;
  #pragma unroll
  for (int k = 0; k < 16; ++k) {
    const float4 w = row[k * 64];
    ss += w.x * w.x + w.y * w.y;
    ss += w.z * w.z + w.w * w.w;
  }

  #pragma unroll
  for (int off = 32; off > 0; off >>= 1) ss += __shfl_down(ss, off, 64);

  if (lane == 0) {
    const float xz = x[z];
    xm[z] = (fabsf(xz) * sqrtf(ss) >= thresh[0]) ? xz : 0.0f;
  }
}

// ---------------- Kernel B: masked GEMV partials ----------------
// grid (ZDIM/ZCHUNK, NF4/256) = (224, 4). Thread t owns one float4 column
// group; loops its 64-row chunk, uniformly skipping masked rows. Writes a
// deterministic partial vector per z-chunk. No barriers, no atomics.
#define ZCHUNK 64

__global__ __launch_bounds__(256) void masked_gemv_part(
    const float* __restrict__ xm,
    const float* __restrict__ Wt,
    float* __restrict__ part) {
  const int t  = threadIdx.x;
  const int z0 = blockIdx.x * ZCHUNK;
  const int cb = blockIdx.y * 256;           // float4 column offset
  const float4* __restrict__ W4 =
      reinterpret_cast<const float4*>(Wt) + cb + t;

  float4 acc = {0.f, 0.f, 0.f, 0.f};

  #pragma unroll 4
  for (int r = 0; r < ZCHUNK; ++r) {
    const float xz = xm[z0 + r];             // block-uniform -> scalar load
    if (xz != 0.0f) {                        // uniform skip of masked rows
      const float4 w = W4[(size_t)(z0 + r) * NF4];
      acc.x = fmaf(xz, w.x, acc.x);
      acc.y = fmaf(xz, w.y, acc.y);
      acc.z = fmaf(xz, w.z, acc.z);
      acc.w = fmaf(xz, w.w, acc.w);
    }
  }

  float4* __restrict__ p4 = reinterpret_cast<float4*>(part);
  p4[(size_t)blockIdx.x * NF4 + cb + t] = acc;
}

// ---------------- Kernel C: reduce partials -> y ----------------
// 1024 threads, thread owns one float4 column group, sums 224 partials
// (coalesced across threads, ~3.7 MB from L2), single write of y.
__global__ __launch_bounds__(256) void reduce_partials(
    const float* __restrict__ part,
    float* __restrict__ y) {
  const int c = blockIdx.x * 256 + threadIdx.x;  // 0..1023 float4 index
  const float4* __restrict__ p4 = reinterpret_cast<const float4*>(part) + c;

  float4 s = {0.f, 0.f, 0.f, 0.f};
  #pragma unroll 8
  for (int j = 0; j < ZDIM / ZCHUNK; ++j) {
    const float4 v = p4[(size_t)j * NF4];
    s.x += v.x; s.y += v.y; s.z += v.z; s.w += v.w;
  }
  reinterpret_cast<float4*>(y)[c] = s;
}

extern "C" void kernel_launch(void* const* d_in, const int* in_sizes, int n_in,
                              void* d_out, int out_size, void* d_ws, size_t ws_size,
                              hipStream_t stream) {
  const float* x      = (const float*)d_in[0];  // [1,1,Z]
  const float* Wt     = (const float*)d_in[1];  // [Z,N]
  const float* thresh = (const float*)d_in[2];  // [1]
  float* y            = (float*)d_out;          // [1,1,N]

  // d_ws layout: xm[Z] floats, then partials [224][N] floats (16B-aligned:
  // 14336*4 = 57344 bytes, divisible by 16).
  float* xm   = (float*)d_ws;
  float* part = (float*)((char*)d_ws + (size_t)ZDIM * sizeof(float));

  rownorm_mask<<<ZDIM / 4, 256, 0, stream>>>(x, Wt, thresh, xm);

  dim3 gridB(ZDIM / ZCHUNK, NF4 / 256);  // (224, 4)
  masked_gemv_part<<<gridB, 256, 0, stream>>>(xm, Wt, part);

  reduce_partials<<<NF4 / 256, 256, 0, stream>>>(part, y);  // (4, 256)
}

// Round 4
// 44.330 us; speedup vs baseline: 3.4475x; 1.5911x over previous
//
#include <hip/hip_runtime.h>
#include <cmath>

// Masked decode-GEMV: y[n] = sum_z m_z * x_z * W_t[z,n],
// m_z = (|x_z| * ||W_t[z,:]||_2 >= thresh).
//
// Single-read fused design (T3/T4 counted-vmcnt pipeline):
//   F: per block, 28 rows streamed through a 4-deep LDS ring via
//      global_load_lds; per row: norm reduce -> mask -> FMA into register
//      partials. Raw s_barrier + counted vmcnt keeps prefetch in flight.
//   C: reduce 512 partial vectors -> y.
// W is read from HBM exactly once (235 MB); no atomics anywhere.

#define ZDIM   14336
#define NDIM   4096
#define NF4    1024       // float4 per row
#define ZCHUNK 28         // rows per block
#define NBLK   512        // ZDIM / ZCHUNK -> exactly 2 blocks per CU
#define DEPTH  4          // LDS ring depth (64 KB)

typedef const __attribute__((address_space(1))) float* gas_fp;
typedef __attribute__((address_space(3))) float* las_fp;

__global__ __launch_bounds__(256) void fused_norm_gemv(
    const float* __restrict__ x,
    const float* __restrict__ Wt,
    const float* __restrict__ thresh,
    float* __restrict__ part) {
  const int t    = threadIdx.x;
  const int lane = t & 63;
  const int wv   = t >> 6;
  const int z0   = blockIdx.x * ZCHUNK;

  __shared__ float ring[DEPTH][NDIM];   // 64 KB row ring
  __shared__ float xs[ZCHUNK];          // x values for this chunk
  __shared__ float red[2][4];           // cross-wave norm partials (parity)

  const float th = thresh[0];
  if (t < ZCHUNK) xs[t] = x[z0 + t];
  __syncthreads();  // drains these loads BEFORE any staging is in flight

  // staging layout is exactly linear: wave wv covers floats
  // [wv*1024 + j*256, +256) of the row, lane contributes 16 B at lane*4.
  const int soff = wv * 1024 + lane * 4;

#define STAGE(slot, zrow) do {                                               \
    const float* gsrc = Wt + (size_t)(zrow) * NDIM + soff;                   \
    float* ldst = &ring[slot][soff];                                         \
    __builtin_amdgcn_global_load_lds((gas_fp)(gsrc      ), (las_fp)(ldst      ), 16, 0, 0); \
    __builtin_amdgcn_global_load_lds((gas_fp)(gsrc + 256), (las_fp)(ldst + 256), 16, 0, 0); \
    __builtin_amdgcn_global_load_lds((gas_fp)(gsrc + 512), (las_fp)(ldst + 512), 16, 0, 0); \
    __builtin_amdgcn_global_load_lds((gas_fp)(gsrc + 768), (las_fp)(ldst + 768), 16, 0, 0); \
  } while (0)

  // prologue: fill the ring (16 vm-ops per wave outstanding)
  STAGE(0, z0 + 0);
  STAGE(1, z0 + 1);
  STAGE(2, z0 + 2);
  STAGE(3, z0 + 3);

  float4 acc0 = {0,0,0,0}, acc1 = {0,0,0,0}, acc2 = {0,0,0,0}, acc3 = {0,0,0,0};

  // Per row: wait own 4 loads (counted, never 0 in steady state) -> barrier
  // (all waves' quarters landed) -> ds_read row into regs -> wave+block norm
  // reduce -> mask -> FMA same regs into acc -> restage freed slot.
#define ROW(r, VM, DO_STAGE) do {                                            \
    asm volatile("s_waitcnt vmcnt(" #VM ")" ::: "memory");                   \
    __builtin_amdgcn_s_barrier();                                            \
    asm volatile("" ::: "memory");                                           \
    const float4* r4 = (const float4*)&ring[(r) & (DEPTH - 1)][0];           \
    const float4 wa = r4[t], wb = r4[t + 256], wc = r4[t + 512], wd = r4[t + 768]; \
    float ssv = wa.x*wa.x + wa.y*wa.y + wa.z*wa.z + wa.w*wa.w                \
              + wb.x*wb.x + wb.y*wb.y + wb.z*wb.z + wb.w*wb.w                \
              + wc.x*wc.x + wc.y*wc.y + wc.z*wc.z + wc.w*wc.w                \
              + wd.x*wd.x + wd.y*wd.y + wd.z*wd.z + wd.w*wd.w;               \
    ssv += __shfl_xor(ssv, 1, 64);                                           \
    ssv += __shfl_xor(ssv, 2, 64);                                           \
    ssv += __shfl_xor(ssv, 4, 64);                                           \
    ssv += __shfl_xor(ssv, 8, 64);                                           \
    ssv += __shfl_xor(ssv, 16, 64);                                          \
    ssv += __shfl_xor(ssv, 32, 64);                                          \
    if (lane == 0) red[(r) & 1][wv] = ssv;                                   \
    asm volatile("s_waitcnt lgkmcnt(0)" ::: "memory");                       \
    __builtin_amdgcn_s_barrier();                                            \
    asm volatile("" ::: "memory");                                           \
    const float n2 = red[(r)&1][0] + red[(r)&1][1] + red[(r)&1][2] + red[(r)&1][3]; \
    const float xz = xs[r];                                                  \
    if (fabsf(xz) * sqrtf(n2) >= th) {  /* wave-uniform branch */            \
      acc0.x = fmaf(xz, wa.x, acc0.x); acc0.y = fmaf(xz, wa.y, acc0.y);      \
      acc0.z = fmaf(xz, wa.z, acc0.z); acc0.w = fmaf(xz, wa.w, acc0.w);      \
      acc1.x = fmaf(xz, wb.x, acc1.x); acc1.y = fmaf(xz, wb.y, acc1.y);      \
      acc1.z = fmaf(xz, wb.z, acc1.z); acc1.w = fmaf(xz, wb.w, acc1.w);      \
      acc2.x = fmaf(xz, wc.x, acc2.x); acc2.y = fmaf(xz, wc.y, acc2.y);      \
      acc2.z = fmaf(xz, wc.z, acc2.z); acc2.w = fmaf(xz, wc.w, acc2.w);      \
      acc3.x = fmaf(xz, wd.x, acc3.x); acc3.y = fmaf(xz, wd.y, acc3.y);      \
      acc3.z = fmaf(xz, wd.z, acc3.z); acc3.w = fmaf(xz, wd.w, acc3.w);      \
    }                                                                        \
    if (DO_STAGE) STAGE((r) & (DEPTH - 1), z0 + (r) + DEPTH);                \
  } while (0)

  #pragma unroll 4
  for (int r = 0; r < ZCHUNK - DEPTH; ++r) ROW(r, 12, 1);
  // drain epilogue: no more staging, counted waits step down to 0
  ROW(24, 12, 0);
  ROW(25, 8, 0);
  ROW(26, 4, 0);
  ROW(27, 0, 0);

  // deterministic partial write (coalesced)
  float4* p4 = (float4*)part + (size_t)blockIdx.x * NF4;
  p4[t]       = acc0;
  p4[t + 256] = acc1;
  p4[t + 512] = acc2;
  p4[t + 768] = acc3;
#undef ROW
#undef STAGE
}

// ---------------- reduce 512 partials -> y ----------------
// grid 256 blocks: block owns 4 float4 columns; thread (jg=t>>2, c=t&3)
// sums 8 partials, then two-stage LDS reduce 64 -> 8 -> 1.
__global__ __launch_bounds__(256) void reduce_parts(
    const float* __restrict__ part, float* __restrict__ y) {
  const int t  = threadIdx.x;
  const int c  = t & 3;
  const int jg = t >> 2;
  const int c4 = blockIdx.x * 4 + c;
  const float4* __restrict__ p4 = (const float4*)part;

  float4 s = {0.f, 0.f, 0.f, 0.f};
  #pragma unroll
  for (int jj = 0; jj < 8; ++jj) {
    const float4 v = p4[(size_t)(jg * 8 + jj) * NF4 + c4];
    s.x += v.x; s.y += v.y; s.z += v.z; s.w += v.w;
  }

  __shared__ float4 sh[64][4];
  sh[jg][c] = s;
  __syncthreads();
  if (jg < 8) {
    #pragma unroll
    for (int k = 1; k < 8; ++k) {
      const float4 v = sh[jg + 8 * k][c];
      s.x += v.x; s.y += v.y; s.z += v.z; s.w += v.w;
    }
    sh[jg][c] = s;
  }
  __syncthreads();
  if (jg == 0) {
    #pragma unroll
    for (int k = 1; k < 8; ++k) {
      const float4 v = sh[k][c];
      s.x += v.x; s.y += v.y; s.z += v.z; s.w += v.w;
    }
    ((float4*)y)[c4] = s;
  }
}

extern "C" void kernel_launch(void* const* d_in, const int* in_sizes, int n_in,
                              void* d_out, int out_size, void* d_ws, size_t ws_size,
                              hipStream_t stream) {
  const float* x      = (const float*)d_in[0];  // [1,1,Z]
  const float* Wt     = (const float*)d_in[1];  // [Z,N]
  const float* thresh = (const float*)d_in[2];  // [1]
  float* y            = (float*)d_out;          // [1,1,N]
  float* part         = (float*)d_ws;           // [NBLK][NDIM] = 8 MB

  fused_norm_gemv<<<NBLK, 256, 0, stream>>>(x, Wt, thresh, part);
  reduce_parts<<<NF4 / 4, 256, 0, stream>>>(part, y);
}